// Round 19
// baseline (93.255 us; speedup 1.0000x reference)
//
#include <hip/hip_runtime.h>
#include <math.h>

#define NNODE 32768     // B*T*N
#define NEDGE 524288    // NNODE * DEG
#define DD 64           // feature dim D
#define E4CAP 622592    // 8 structures x 77824 padded slots
#define SSTRIDE 77824   // padded slot stride per structure
#define RP4S 4100       // rowptr4 row stride per structure

typedef float  f32x4 __attribute__((ext_vector_type(4)));
typedef short  s16x8 __attribute__((ext_vector_type(8)));
typedef short  s16x4 __attribute__((ext_vector_type(4)));

__device__ __forceinline__ float silu_f(float x) {
    return x * __builtin_amdgcn_rcpf(1.0f + __expf(-x));
}
__device__ __forceinline__ unsigned cvt_pk_bf16(float a, float b) {
    unsigned r;
    asm("v_cvt_pk_bf16_f32 %0, %1, %2" : "=v"(r) : "v"(a), "v"(b));
    return r;
}
__device__ __forceinline__ unsigned short bf16r(float f) {
    unsigned u = __float_as_uint(f);
    unsigned r = (u + 0x7FFFu + ((u >> 16) & 1u)) >> 16;
    return (unsigned short)r;
}
__device__ __forceinline__ float bf16f(unsigned short u) {
    return __uint_as_float(((unsigned)u) << 16);
}
__device__ __forceinline__ void wsync() {
    asm volatile("s_waitcnt lgkmcnt(0)" ::: "memory");
    __builtin_amdgcn_sched_barrier(0);
}

// 16x16x16 bf16 MFMA (K=16): builtin if present, else inline asm
#if defined(__has_builtin) && __has_builtin(__builtin_amdgcn_mfma_f32_16x16x16bf16_1k)
#define MFMA16(a,b,c) __builtin_amdgcn_mfma_f32_16x16x16bf16_1k((a),(b),(c),0,0,0)
#else
__device__ __forceinline__ f32x4 mfma16_asm(s16x4 a, s16x4 b, f32x4 c) {
    asm("v_mfma_f32_16x16x16_bf16 %0, %1, %2, %0" : "+v"(c) : "v"(a), "v"(b));
    return c;
}
#define MFMA16(a,b,c) mfma16_asm((a),(b),(c))
#endif

// fused: pos prep (0..127) + XCD-swizzled dst histogram/rank (0..2047)
//        + wfrag (2048..2055) + base (2056)
__global__ __launch_bounds__(256) void k_prep_hist_base(
    const float* __restrict__ x, const float* __restrict__ x1,
    const float* __restrict__ vm, float* __restrict__ pos,
    const int* __restrict__ ei, int* __restrict__ cnt, int* __restrict__ rank,
    const float* __restrict__ Wsp, const float* __restrict__ Wt,
    const float* __restrict__ Wm, const float* __restrict__ Wu,
    const float* __restrict__ We, const float* __restrict__ tarr,
    float* __restrict__ base_ws, unsigned short* __restrict__ wfrag)
{
    int tid = threadIdx.x, b = blockIdx.x;
    if (b >= 2048) {
        if (b < 2056) {
            #pragma unroll
            for (int j = 0; j < 5; ++j) {
                int idx = (b - 2048) * 1280 + j * 256 + tid;
                unsigned short v;
                if (idx < 8192) {
                    int sel = idx >> 12, id2 = idx & 4095;
                    int jj = id2 & 7;
                    int ln = (id2 >> 3) & 63;
                    int ts = id2 >> 9;
                    int t2 = ts >> 1, s = ts & 1;
                    int k   = s*32 + (ln >> 4)*8 + jj;
                    int col = t2*16 + (ln & 15);
                    v = bf16r(sel ? Wu[k*DD + col] : Wm[(128 + k)*DD + col]);
                } else {
                    int id3 = idx - 8192;
                    int jj = id3 & 7, ln = (id3 >> 3) & 63, t2 = id3 >> 9;
                    v = (ln < 16 && jj < 4) ? bf16r(We[jj*DD + t2*16 + (ln & 15)])
                                            : (unsigned short)0;
                }
                wfrag[idx] = v;
            }
        } else if (tid < 64) {
            float t0 = tarr[0], t1 = tarr[1];
            float aA = 0.0f, aB = 0.0f;
            #pragma unroll 8
            for (int k = 0; k < DD; ++k) {
                float w = Wm[k*DD + tid] + Wm[(DD+k)*DD + tid];
                aA = fmaf(Wsp[k] + t0*Wt[k], w, aA);
                aB = fmaf(Wsp[k] + t1*Wt[k], w, aB);
            }
            base_ws[tid]      = aA;
            base_ws[DD + tid] = aB;
        }
        return;
    }
    if (b < 128) {
        int i = b*256 + tid;
        float m = vm[i];
        #pragma unroll
        for (int c = 0; c < 3; ++c)
            pos[i*3+c] = x[i*3+c]*m + x1[i*3+c]*(1.0f-m);
    }
    int e = (b & 7) * 65536 + (b >> 3) * 256 + tid;
    rank[e] = atomicAdd(&cnt[ei[NEDGE + e]], 1);
}

// per-structure dual exclusive scan: rowptr (real) + rowptr4 (x4-padded)
__global__ __launch_bounds__(1024) void k_scan(
    const int* __restrict__ cnt, int* __restrict__ rowptr, int* __restrict__ rowptr4)
{
    __shared__ int buf[2][1024];
    const int g = blockIdx.x;          // 8 blocks
    const int tid = threadIdx.x;
    int4 L = ((const int4*)cnt)[g*1024 + tid];
    int s = L.x + L.y + L.z + L.w;
    buf[0][tid] = s;
    __syncthreads();
    int pp = 0;
    for (int off = 1; off < 1024; off <<= 1) {
        int v = buf[pp][tid];
        if (tid >= off) v += buf[pp][tid - off];
        buf[pp^1][tid] = v;
        __syncthreads();
        pp ^= 1;
    }
    int ex = (tid ? buf[pp][tid-1] : 0) + g*65536;
    int4 o;
    o.x = ex; ex += L.x;
    o.y = ex; ex += L.y;
    o.z = ex; ex += L.z;
    o.w = ex; ex += L.w;
    ((int4*)rowptr)[g*1024 + tid] = o;
    if (g == 7 && tid == 1023) rowptr[32768] = NEDGE;
    __syncthreads();
    int4 P = { (L.x+3)&~3, (L.y+3)&~3, (L.z+3)&~3, (L.w+3)&~3 };
    int s4 = P.x + P.y + P.z + P.w;
    buf[0][tid] = s4;
    __syncthreads();
    pp = 0;
    for (int off = 1; off < 1024; off <<= 1) {
        int v = buf[pp][tid];
        if (tid >= off) v += buf[pp][tid - off];
        buf[pp^1][tid] = v;
        __syncthreads();
        pp ^= 1;
    }
    int ex4 = (tid ? buf[pp][tid-1] : 0) + g*SSTRIDE;
    int4 o4;
    o4.x = ex4; ex4 += P.x;
    o4.y = ex4; ex4 += P.y;
    o4.z = ex4; ex4 += P.z;
    o4.w = ex4; ex4 += P.w;
    *(int4*)(rowptr4 + g*RP4S + tid*4) = o4;
    if (tid == 1023) rowptr4[g*RP4S + 4096] = ex4;
}

// geometry + counting-sort scatter into padded slots (pad slots stay zero)
__global__ __launch_bounds__(256) void k_sortgeo(
    const int* __restrict__ ei, const int* __restrict__ tj,
    const float* __restrict__ pos, const float* __restrict__ cell,
    const int* __restrict__ rowptr4, const int* __restrict__ rank,
    float4* __restrict__ srec4)
{
    int b = blockIdx.x;                              // 2048 blocks, XCD-swizzled
    int e = (b & 7) * 65536 + (b >> 3) * 256 + threadIdx.x;
    int g = b & 7;
    int src = ei[e];
    int dst = ei[NEDGE + e];
    const float* cl = cell + g*9;
    float c00=cl[0],c01=cl[1],c02=cl[2],c10=cl[3],c11=cl[4],c12=cl[5],c20=cl[6],c21=cl[7],c22=cl[8];
    float tj0 = (float)tj[e*3+0], tj1 = (float)tj[e*3+1], tj2 = (float)tj[e*3+2];
    float ev0 = pos[dst*3+0] - pos[src*3+0] + tj0*c00 + tj1*c10 + tj2*c20;
    float ev1 = pos[dst*3+1] - pos[src*3+1] + tj0*c01 + tj1*c11 + tj2*c21;
    float ev2 = pos[dst*3+2] - pos[src*3+2] + tj0*c02 + tj1*c12 + tj2*c22;
    float len = sqrtf(ev0*ev0 + ev1*ev1 + ev2*ev2 + 1e-12f);
    int slot = rowptr4[g*RP4S + (dst & 4095)] + rank[e];
    srec4[slot] = (float4){ev0, ev1, ev2, len};
}

// One wave per 4-node group (8192 blocks). x4-padded CSR: chunk (4 slots) = one
// node = lane-quarter hi. V+agg via 16x16x16 MFMA: A = evT rows {x,y,z,1},
// B = msg-MFMA D output (registers, no LDS round-trip); per-node masking via
// cndmask on scalar chunk bounds. Accumulators in VGPRs; dump once at end.
__global__ __launch_bounds__(64, 3) void k_edge_all(
    const float4* __restrict__ srec4,
    const int* __restrict__ rowptr, const int* __restrict__ rowptr4,
    const unsigned short* __restrict__ wfrag,
    const float* __restrict__ base_ws,
    const float* __restrict__ Wsp, const float* __restrict__ Wt,
    const float* __restrict__ wdec, const float* __restrict__ tarr,
    const float* __restrict__ vm, float* __restrict__ out)
{
    const int lane = threadIdx.x;
    const int lo16 = lane & 15;
    const int hi   = lane >> 4;
    const int grp  = (blockIdx.x & 7) * 1024 + (blockIdx.x >> 3);  // XCD slice
    const int n0   = grp * 4;

    // LDS 6272 B:
    // @0 edge4 f4[64] (1024) | @1024 evT u16[4][72] (576) | @1600 ealds u16[16][72] (2304)
    // @3904 agg_l u16[4][72] (576) | @4480 v_l u16[12][64] (1536) | pad (A-read overrun guarded)
    __shared__ __align__(16) char my[6272];
    float4*         edge4 = (float4*)my;
    unsigned short* evT   = (unsigned short*)(my + 1024);
    unsigned short* ealds = (unsigned short*)(my + 1600);
    unsigned short* agg_l = (unsigned short*)(my + 3904);
    unsigned short* v_l   = (unsigned short*)(my + 4480);

    // evT row 3 = ones (agg via the same MFMA)
    evT[3*72 + lane] = 0x3F80;

    // accumulators: acc[node][ch-tile], rows {x,y,z,agg} live in lanes hi==0
    f32x4 accv[4][4] = {};

    // weights
    s16x8 bfr[4][2], wfe[4];
    #pragma unroll
    for (int t2 = 0; t2 < 4; ++t2) {
        #pragma unroll
        for (int s = 0; s < 2; ++s)
            bfr[t2][s] = *(const s16x8*)(wfrag + ((t2*2+s)*64 + lane)*8);
        wfe[t2] = *(const s16x8*)(wfrag + 8192 + (t2*64 + lane)*8);
    }
    const bool  sb  = (n0 >> 14) != 0;         // batch
    float bv4[4];
    #pragma unroll
    for (int t2 = 0; t2 < 4; ++t2)
        bv4[t2] = base_ws[(sb ? DD : 0) + t2*16 + lo16];

    // scalar CSR bounds (padded + real)
    const int gS = n0 >> 12;
    const int li = gS*RP4S + (n0 & 4095);
    int rp4a[5], npad[4];
    #pragma unroll
    for (int k = 0; k <= 4; ++k)
        rp4a[k] = __builtin_amdgcn_readfirstlane(rowptr4[li + k]);
    #pragma unroll
    for (int k = 0; k < 4; ++k) {
        int r0 = __builtin_amdgcn_readfirstlane(rowptr[n0 + k]);
        int r1 = __builtin_amdgcn_readfirstlane(rowptr[n0 + k + 1]);
        npad[k] = (rp4a[k+1] - rp4a[k]) - (r1 - r0);
    }

    const int estart = rp4a[0];
    const int eend   = rp4a[4];

    int ebase = estart;
    int cnt64 = eend - ebase; if (cnt64 > 64) cnt64 = 64;
    float4 r_rec = {0.f,0.f,0.f,0.f};
    if (ebase < eend) {
        int ii = ebase + (lane < cnt64 ? lane : cnt64 - 1);
        r_rec = srec4[ii];
    }

    while (ebase < eend) {
        edge4[lane] = r_rec;
        // evT rows 0..2: this window's ev components, col = slot (lane)
        evT[0*72 + lane] = (unsigned short)cvt_pk_bf16(r_rec.x, 0.f);
        evT[1*72 + lane] = (unsigned short)cvt_pk_bf16(r_rec.y, 0.f);
        evT[2*72 + lane] = (unsigned short)cvt_pk_bf16(r_rec.z, 0.f);

        // prefetch next window
        int nb = ebase + 64;
        if (nb < eend) {
            int c2 = eend - nb; if (c2 > 64) c2 = 64;
            int jj = nb + (lane < c2 ? lane : c2 - 1);
            r_rec = srec4[jj];
        }

        int nsub = (cnt64 + 15) >> 4;
        for (int i = 0; i < nsub; ++i) {
            const int s0 = ebase + i*16;

            // ---- ea stage via MFMA (K=4 in a 16x16x32) ----
            float4 q = edge4[i*16 + lo16];
            unsigned pa0 = cvt_pk_bf16(q.x, q.y);
            unsigned pa1 = cvt_pk_bf16(q.z, q.w);
            uint4 av = (hi == 0) ? (uint4){pa0, pa1, 0u, 0u}
                                 : (uint4){0u, 0u, 0u, 0u};
            s16x8 aea = *reinterpret_cast<s16x8*>(&av);
            #pragma unroll
            for (int t2 = 0; t2 < 4; ++t2) {
                f32x4 pre = {0.f, 0.f, 0.f, 0.f};
                pre = __builtin_amdgcn_mfma_f32_16x16x32_bf16(aea, wfe[t2], pre, 0, 0, 0);
                #pragma unroll
                for (int r = 0; r < 4; ++r)
                    ealds[(hi*4+r)*72 + t2*16 + lo16] =
                        (unsigned short)cvt_pk_bf16(silu_f(pre[r]), 0.f);
            }
            const unsigned short* arow = ealds + lo16*72 + hi*8;
            s16x8 a0 = *(const s16x8*)(arow);
            s16x8 a1 = *(const s16x8*)(arow + 32);

            // ---- msg MFMAs; D output stays in registers as V-MFMA B-frags ----
            s16x4 Bf[4];
            #pragma unroll
            for (int t2 = 0; t2 < 4; ++t2) {
                const float bvt = bv4[t2];
                f32x4 acc = {bvt, bvt, bvt, bvt};
                acc = __builtin_amdgcn_mfma_f32_16x16x32_bf16(a0, bfr[t2][0], acc, 0, 0, 0);
                acc = __builtin_amdgcn_mfma_f32_16x16x32_bf16(a1, bfr[t2][1], acc, 0, 0, 0);
                unsigned u0 = cvt_pk_bf16(silu_f(acc[0]), silu_f(acc[1]));
                unsigned u1 = cvt_pk_bf16(silu_f(acc[2]), silu_f(acc[3]));
                union { uint2 u2; s16x4 s4; } cv;
                cv.u2 = (uint2){u0, u1};
                Bf[t2] = cv.s4;
            }

            // ---- V+agg MFMAs: A = evT (rows x,y,z,1), k-chunk = hi ----
            s16x4 a_ev = *(const s16x4*)(evT + lo16*72 + i*16 + hi*4);
            const int sc = s0 + hi*4;               // this lane's chunk slot
            int nlv = (sc >= rp4a[1]) + (sc >= rp4a[2]) + (sc >= rp4a[3]) + (sc >= rp4a[4]);
            int nf  = (s0 >= rp4a[1]) + (s0 >= rp4a[2]) + (s0 >= rp4a[3]);
            int s3  = s0 + 12;
            int nl_ = (s3 >= rp4a[1]) + (s3 >= rp4a[2]) + (s3 >= rp4a[3]);
            s16x4 zz = {0,0,0,0};
            #pragma unroll
            for (int n = 0; n < 4; ++n) {
                if (n >= nf && n <= nl_) {          // wave-uniform
                    bool msk = (nlv == n);
                    s16x4 Am = msk ? a_ev : zz;
                    accv[n][0] = MFMA16(Am, Bf[0], accv[n][0]);
                    accv[n][1] = MFMA16(Am, Bf[1], accv[n][1]);
                    accv[n][2] = MFMA16(Am, Bf[2], accv[n][2]);
                    accv[n][3] = MFMA16(Am, Bf[3], accv[n][3]);
                }
            }
        }
        ebase = nb;
        cnt64 = eend - ebase; if (cnt64 > 64) cnt64 = 64;
    }

    // ---- dump acc (lanes hi==0 hold rows x,y,z,agg) + pad correction ----
    float sb4[4];
    #pragma unroll
    for (int t2 = 0; t2 < 4; ++t2)
        sb4[t2] = bf16f(bf16r(silu_f(bv4[t2])));   // exact pad msg value
    if (hi == 0) {
        #pragma unroll
        for (int n = 0; n < 4; ++n) {
            #pragma unroll
            for (int t2 = 0; t2 < 4; ++t2) {
                float ag = accv[n][t2][3] - (float)npad[n] * sb4[t2];
                agg_l[n*72 + t2*16 + lo16]       = (unsigned short)cvt_pk_bf16(ag, ag);
                v_l[(n*3+0)*64 + t2*16 + lo16]   = (unsigned short)cvt_pk_bf16(accv[n][t2][0], 0.f);
                v_l[(n*3+1)*64 + t2*16 + lo16]   = (unsigned short)cvt_pk_bf16(accv[n][t2][1], 0.f);
                v_l[(n*3+2)*64 + t2*16 + lo16]   = (unsigned short)cvt_pk_bf16(accv[n][t2][2], 0.f);
            }
        }
    }
    wsync();

    // ---- node phase: gate = silu(h + silu(agg@Wu)) * wdec; out = vm * (v . gate) ----
    s16x8 wub[4][2];
    #pragma unroll
    for (int t2 = 0; t2 < 4; ++t2)
        #pragma unroll
        for (int s = 0; s < 2; ++s)
            wub[t2][s] = *(const s16x8*)(wfrag + 4096 + ((t2*2+s)*64 + lane)*8);
    const float tb = sb ? tarr[1] : tarr[0];
    float hb4[4], wd4[4];
    #pragma unroll
    for (int t2 = 0; t2 < 4; ++t2) {
        hb4[t2] = Wsp[t2*16+lo16] + tb * Wt[t2*16+lo16];
        wd4[t2] = wdec[t2*16+lo16];
    }
    s16x8 ga0 = *(const s16x8*)(agg_l + lo16*72 + hi*8);   // rows>=4 garbage, guarded
    s16x8 ga1 = *(const s16x8*)(agg_l + lo16*72 + hi*8 + 32);
    float p[4][3] = {{0.f,0.f,0.f},{0.f,0.f,0.f},{0.f,0.f,0.f},{0.f,0.f,0.f}};
    #pragma unroll
    for (int t2 = 0; t2 < 4; ++t2) {
        f32x4 accg = {0.f, 0.f, 0.f, 0.f};
        accg = __builtin_amdgcn_mfma_f32_16x16x32_bf16(ga0, wub[t2][0], accg, 0, 0, 0);
        accg = __builtin_amdgcn_mfma_f32_16x16x32_bf16(ga1, wub[t2][1], accg, 0, 0, 0);
        #pragma unroll
        for (int r = 0; r < 4; ++r) {
            int node = hi*4 + r;
            float hn   = hb4[t2] + silu_f(accg[r]);
            float gate = silu_f(hn) * wd4[t2];
            if (node < 4) {
                #pragma unroll
                for (int c = 0; c < 3; ++c) {
                    float vv = bf16f(v_l[(node*3+c)*64 + t2*16 + lo16]);
                    p[r][c] = fmaf(gate, vv, p[r][c]);
                }
            }
        }
    }
    #pragma unroll
    for (int st = 1; st < 16; st <<= 1)
        #pragma unroll
        for (int r = 0; r < 4; ++r)
            #pragma unroll
            for (int c = 0; c < 3; ++c)
                p[r][c] += __shfl_xor(p[r][c], st, 64);

    if (lo16 < 12 && hi == 0) {
        int rr = lo16 / 3, c = lo16 - rr*3;
        float val = rr==0 ? (c==0 ? p[0][0] : c==1 ? p[0][1] : p[0][2])
                  : rr==1 ? (c==0 ? p[1][0] : c==1 ? p[1][1] : p[1][2])
                  : rr==2 ? (c==0 ? p[2][0] : c==1 ? p[2][1] : p[2][2])
                  :         (c==0 ? p[3][0] : c==1 ? p[3][1] : p[3][2]);
        out[(n0 + rr)*3 + c] = val * vm[n0 + rr];
    }
}

extern "C" void kernel_launch(void* const* d_in, const int* in_sizes, int n_in,
                              void* d_out, int out_size, void* d_ws, size_t ws_size,
                              hipStream_t stream) {
    const float* x    = (const float*)d_in[0];
    const float* t    = (const float*)d_in[1];
    const float* cell = (const float*)d_in[2];
    const float* x1   = (const float*)d_in[3];
    const float* vm   = (const float*)d_in[4];
    const float* Wsp  = (const float*)d_in[5];
    const float* Wt   = (const float*)d_in[6];
    const float* We   = (const float*)d_in[7];
    const float* Wm   = (const float*)d_in[8];
    const float* Wu   = (const float*)d_in[9];
    const float* wdec = (const float*)d_in[10];
    const int*   ei   = (const int*)d_in[11];
    const int*   tj   = (const int*)d_in[12];
    float* out = (float*)d_out;

    // ws layout (float units):
    float*  ws      = (float*)d_ws;
    float4* srec4   = (float4*)ws;                       // [E4CAP] f4 = 2490368 f
    float*  pos     = ws + 2490368;                      // [98304]
    int*    rank    = (int*)(pos + 98304);               // [524288]
    int*    rowptr  = rank + 524288;                     // [32772 pad]
    int*    rowptr4 = rowptr + 32772;                    // [8*RP4S = 32800]
    int*    cnt     = rowptr4 + 32800;                   // [32768]
    float*  base_ws = (float*)(cnt + 32768);             // [128]
    unsigned short* wfrag = (unsigned short*)(base_ws + 128);  // [10240]

    hipMemsetAsync(cnt, 0, 32768*sizeof(int), stream);
    hipMemsetAsync(srec4, 0, (size_t)E4CAP*16, stream);
    k_prep_hist_base<<<2057, 256, 0, stream>>>(x, x1, vm, pos, ei, cnt, rank,
                                               Wsp, Wt, Wm, Wu, We, t, base_ws, wfrag);
    k_scan<<<8, 1024, 0, stream>>>(cnt, rowptr, rowptr4);
    k_sortgeo<<<2048, 256, 0, stream>>>(ei, tj, pos, cell, rowptr4, rank, srec4);
    k_edge_all<<<8192, 64, 0, stream>>>(srec4, rowptr, rowptr4, wfrag, base_ws,
                                        Wsp, Wt, wdec, t, vm, out);
}

// Round 20
// 81.894 us; speedup vs baseline: 1.1387x; 1.1387x over previous
//
#include <hip/hip_runtime.h>
#include <math.h>

#define NNODE 32768     // B*T*N
#define NEDGE 524288    // NNODE * DEG
#define DD 64           // feature dim D
#define SSTRIDE 77824   // padded slot stride per structure
#define RP4S 4100       // rowptr4 row stride per structure

typedef float  f32x4 __attribute__((ext_vector_type(4)));
typedef short  s16x8 __attribute__((ext_vector_type(8)));
typedef short  s16x4 __attribute__((ext_vector_type(4)));

__device__ __forceinline__ float silu_f(float x) {
    return x * __builtin_amdgcn_rcpf(1.0f + __expf(-x));
}
__device__ __forceinline__ unsigned cvt_pk_bf16(float a, float b) {
    unsigned r;
    asm("v_cvt_pk_bf16_f32 %0, %1, %2" : "=v"(r) : "v"(a), "v"(b));
    return r;
}
__device__ __forceinline__ unsigned short bf16r(float f) {
    unsigned u = __float_as_uint(f);
    unsigned r = (u + 0x7FFFu + ((u >> 16) & 1u)) >> 16;
    return (unsigned short)r;
}
__device__ __forceinline__ float bf16f(unsigned short u) {
    return __uint_as_float(((unsigned)u) << 16);
}
__device__ __forceinline__ void wsync() {
    asm volatile("s_waitcnt lgkmcnt(0)" ::: "memory");
    __builtin_amdgcn_sched_barrier(0);
}

// 16x16x16 bf16 MFMA (K=16): builtin if present, else inline asm (r19-validated)
#if defined(__has_builtin) && __has_builtin(__builtin_amdgcn_mfma_f32_16x16x16bf16_1k)
#define MFMA16(a,b,c) __builtin_amdgcn_mfma_f32_16x16x16bf16_1k((a),(b),(c),0,0,0)
#else
__device__ __forceinline__ f32x4 mfma16_asm(s16x4 a, s16x4 b, f32x4 c) {
    asm("v_mfma_f32_16x16x16_bf16 %0, %1, %2, %0" : "+v"(c) : "v"(a), "v"(b));
    return c;
}
#define MFMA16(a,b,c) mfma16_asm((a),(b),(c))
#endif

// fused: pos prep (0..127) + XCD-swizzled dst histogram/rank (0..2047)
//        + wfrag (2048..2055) + base (2056)
__global__ __launch_bounds__(256) void k_prep_hist_base(
    const float* __restrict__ x, const float* __restrict__ x1,
    const float* __restrict__ vm, float* __restrict__ pos,
    const int* __restrict__ ei, int* __restrict__ cnt, int* __restrict__ rank,
    const float* __restrict__ Wsp, const float* __restrict__ Wt,
    const float* __restrict__ Wm, const float* __restrict__ Wu,
    const float* __restrict__ We, const float* __restrict__ tarr,
    float* __restrict__ base_ws, unsigned short* __restrict__ wfrag)
{
    int tid = threadIdx.x, b = blockIdx.x;
    if (b >= 2048) {
        if (b < 2056) {
            #pragma unroll
            for (int j = 0; j < 5; ++j) {
                int idx = (b - 2048) * 1280 + j * 256 + tid;
                unsigned short v;
                if (idx < 8192) {
                    int sel = idx >> 12, id2 = idx & 4095;
                    int jj = id2 & 7;
                    int ln = (id2 >> 3) & 63;
                    int ts = id2 >> 9;
                    int t2 = ts >> 1, s = ts & 1;
                    int k   = s*32 + (ln >> 4)*8 + jj;
                    int col = t2*16 + (ln & 15);
                    v = bf16r(sel ? Wu[k*DD + col] : Wm[(128 + k)*DD + col]);
                } else {
                    int id3 = idx - 8192;
                    int jj = id3 & 7, ln = (id3 >> 3) & 63, t2 = id3 >> 9;
                    v = (ln < 16 && jj < 4) ? bf16r(We[jj*DD + t2*16 + (ln & 15)])
                                            : (unsigned short)0;
                }
                wfrag[idx] = v;
            }
        } else if (tid < 64) {
            float t0 = tarr[0], t1 = tarr[1];
            float aA = 0.0f, aB = 0.0f;
            #pragma unroll 8
            for (int k = 0; k < DD; ++k) {
                float w = Wm[k*DD + tid] + Wm[(DD+k)*DD + tid];
                aA = fmaf(Wsp[k] + t0*Wt[k], w, aA);
                aB = fmaf(Wsp[k] + t1*Wt[k], w, aB);
            }
            base_ws[tid]      = aA;
            base_ws[DD + tid] = aB;
        }
        return;
    }
    if (b < 128) {
        int i = b*256 + tid;
        float m = vm[i];
        #pragma unroll
        for (int c = 0; c < 3; ++c)
            pos[i*3+c] = x[i*3+c]*m + x1[i*3+c]*(1.0f-m);
    }
    int e = (b & 7) * 65536 + (b >> 3) * 256 + tid;
    rank[e] = atomicAdd(&cnt[ei[NEDGE + e]], 1);
}

// per-structure dual exclusive scan: rowptr (real) + rowptr4 (x4-padded)
__global__ __launch_bounds__(1024) void k_scan(
    const int* __restrict__ cnt, int* __restrict__ rowptr, int* __restrict__ rowptr4)
{
    __shared__ int buf[2][1024];
    const int g = blockIdx.x;          // 8 blocks
    const int tid = threadIdx.x;
    int4 L = ((const int4*)cnt)[g*1024 + tid];
    int s = L.x + L.y + L.z + L.w;
    buf[0][tid] = s;
    __syncthreads();
    int pp = 0;
    for (int off = 1; off < 1024; off <<= 1) {
        int v = buf[pp][tid];
        if (tid >= off) v += buf[pp][tid - off];
        buf[pp^1][tid] = v;
        __syncthreads();
        pp ^= 1;
    }
    int ex = (tid ? buf[pp][tid-1] : 0) + g*65536;
    int4 o;
    o.x = ex; ex += L.x;
    o.y = ex; ex += L.y;
    o.z = ex; ex += L.z;
    o.w = ex; ex += L.w;
    ((int4*)rowptr)[g*1024 + tid] = o;
    if (g == 7 && tid == 1023) rowptr[32768] = NEDGE;
    __syncthreads();
    int4 P = { (L.x+3)&~3, (L.y+3)&~3, (L.z+3)&~3, (L.w+3)&~3 };
    int s4 = P.x + P.y + P.z + P.w;
    buf[0][tid] = s4;
    __syncthreads();
    pp = 0;
    for (int off = 1; off < 1024; off <<= 1) {
        int v = buf[pp][tid];
        if (tid >= off) v += buf[pp][tid - off];
        buf[pp^1][tid] = v;
        __syncthreads();
        pp ^= 1;
    }
    int ex4 = (tid ? buf[pp][tid-1] : 0) + g*SSTRIDE;
    int4 o4;
    o4.x = ex4; ex4 += P.x;
    o4.y = ex4; ex4 += P.y;
    o4.z = ex4; ex4 += P.z;
    o4.w = ex4; ex4 += P.w;
    *(int4*)(rowptr4 + g*RP4S + tid*4) = o4;
    if (tid == 1023) rowptr4[g*RP4S + 4096] = ex4;
}

// geometry + counting-sort scatter into padded slots (blocks 0..2047, XCD-swizzled)
// + pad-slot zeroing (blocks 2048..2175: one thread per node, <=3 f4 stores)
__global__ __launch_bounds__(256) void k_sortgeo(
    const int* __restrict__ ei, const int* __restrict__ tj,
    const float* __restrict__ pos, const float* __restrict__ cell,
    const int* __restrict__ rowptr, const int* __restrict__ rowptr4,
    const int* __restrict__ rank, float4* __restrict__ srec4)
{
    int b = blockIdx.x;
    if (b >= 2048) {
        int n  = (b - 2048) * 256 + threadIdx.x;     // node 0..32767
        int g  = n >> 12;
        int li = g*RP4S + (n & 4095);
        int s0 = rowptr4[li];
        int s1 = rowptr4[li + 1];
        int deg = rowptr[n + 1] - rowptr[n];
        for (int s = s0 + deg; s < s1; ++s)
            srec4[s] = (float4){0.f, 0.f, 0.f, 0.f};
        return;
    }
    int e = (b & 7) * 65536 + (b >> 3) * 256 + threadIdx.x;
    int g = b & 7;
    int src = ei[e];
    int dst = ei[NEDGE + e];
    const float* cl = cell + g*9;
    float c00=cl[0],c01=cl[1],c02=cl[2],c10=cl[3],c11=cl[4],c12=cl[5],c20=cl[6],c21=cl[7],c22=cl[8];
    float tj0 = (float)tj[e*3+0], tj1 = (float)tj[e*3+1], tj2 = (float)tj[e*3+2];
    float ev0 = pos[dst*3+0] - pos[src*3+0] + tj0*c00 + tj1*c10 + tj2*c20;
    float ev1 = pos[dst*3+1] - pos[src*3+1] + tj0*c01 + tj1*c11 + tj2*c21;
    float ev2 = pos[dst*3+2] - pos[src*3+2] + tj0*c02 + tj1*c12 + tj2*c22;
    float len = sqrtf(ev0*ev0 + ev1*ev1 + ev2*ev2 + 1e-12f);
    int slot = rowptr4[g*RP4S + (dst & 4095)] + rank[e];
    srec4[slot] = (float4){ev0, ev1, ev2, len};
}

// One wave per 4-node group (8192 blocks). x4-padded CSR. Masked evT A-tile:
// row 4n+r holds ev_r only in columns of node n (zeros elsewhere). ONE
// 16x16x16 MFMA per ch-tile per subtile computes v(x,y,z)+agg for ALL 4 nodes:
// D row 4*hi+reg -> lane quarter hi owns node hi. acc = 16 VGPRs, no masks,
// no per-edge LDS reads, no segred.
__global__ __launch_bounds__(64) void k_edge_all(
    const float4* __restrict__ srec4,
    const int* __restrict__ rowptr, const int* __restrict__ rowptr4,
    const unsigned short* __restrict__ wfrag,
    const float* __restrict__ base_ws,
    const float* __restrict__ Wsp, const float* __restrict__ Wt,
    const float* __restrict__ wdec, const float* __restrict__ tarr,
    const float* __restrict__ vm, float* __restrict__ out)
{
    const int lane = threadIdx.x;
    const int lo16 = lane & 15;
    const int hi   = lane >> 4;
    const int grp  = (blockIdx.x & 7) * 1024 + (blockIdx.x >> 3);  // XCD slice
    const int n0   = grp * 4;

    // LDS 7936 B:
    // @0 edge4 f4[64] (1024) | @1024 evT u16[16][72] (2304) | @3328 ealds u16[16][72] (2304)
    // @5632 agg_l u16[4][72] (576) | @6208 v_l u16[12][64] (1536) | pad (A-read overrun)
    __shared__ __align__(16) char my[7936];
    float4*         edge4 = (float4*)my;
    unsigned short* evT   = (unsigned short*)(my + 1024);
    unsigned short* ealds = (unsigned short*)(my + 3328);
    unsigned short* agg_l = (unsigned short*)(my + 5632);
    unsigned short* v_l   = (unsigned short*)(my + 6208);

    // accumulators: acc[t2][reg] — lane quarter hi = node hi, reg = {x,y,z,agg}
    f32x4 acc[4] = {};

    // weights
    s16x8 bfr[4][2], wfe[4];
    #pragma unroll
    for (int t2 = 0; t2 < 4; ++t2) {
        #pragma unroll
        for (int s = 0; s < 2; ++s)
            bfr[t2][s] = *(const s16x8*)(wfrag + ((t2*2+s)*64 + lane)*8);
        wfe[t2] = *(const s16x8*)(wfrag + 8192 + (t2*64 + lane)*8);
    }
    const bool  sb  = (n0 >> 14) != 0;         // batch
    float bv4[4];
    #pragma unroll
    for (int t2 = 0; t2 < 4; ++t2)
        bv4[t2] = base_ws[(sb ? DD : 0) + t2*16 + lo16];

    // scalar CSR bounds (padded + real)
    const int gS = n0 >> 12;
    const int li = gS*RP4S + (n0 & 4095);
    int rp4a[5], npad[4];
    #pragma unroll
    for (int k = 0; k <= 4; ++k)
        rp4a[k] = __builtin_amdgcn_readfirstlane(rowptr4[li + k]);
    #pragma unroll
    for (int k = 0; k < 4; ++k) {
        int r0 = __builtin_amdgcn_readfirstlane(rowptr[n0 + k]);
        int r1 = __builtin_amdgcn_readfirstlane(rowptr[n0 + k + 1]);
        npad[k] = (rp4a[k+1] - rp4a[k]) - (r1 - r0);
    }

    const int estart = rp4a[0];
    const int eend   = rp4a[4];

    int ebase = estart;
    int cnt64 = eend - ebase; if (cnt64 > 64) cnt64 = 64;
    float4 r_rec = {0.f,0.f,0.f,0.f};
    if (ebase < eend) {
        int ii = ebase + (lane < cnt64 ? lane : cnt64 - 1);
        r_rec = srec4[ii];
    }

    while (ebase < eend) {
        float4 cur = r_rec;
        edge4[lane] = cur;
        // build masked evT: zero all 16 rows, then write this lane's node rows
        {
            int* ez = (int*)evT;
            #pragma unroll
            for (int j = 0; j < 9; ++j) ez[j*64 + lane] = 0;
        }
        if (lane < cnt64) {
            int slot = ebase + lane;
            int nd = (slot >= rp4a[1]) + (slot >= rp4a[2]) + (slot >= rp4a[3]);
            evT[(nd*4+0)*72 + lane] = (unsigned short)cvt_pk_bf16(cur.x, 0.f);
            evT[(nd*4+1)*72 + lane] = (unsigned short)cvt_pk_bf16(cur.y, 0.f);
            evT[(nd*4+2)*72 + lane] = (unsigned short)cvt_pk_bf16(cur.z, 0.f);
            evT[(nd*4+3)*72 + lane] = 0x3F80;   // 1.0 -> agg row
        }

        // prefetch next window
        int nb = ebase + 64;
        if (nb < eend) {
            int c2 = eend - nb; if (c2 > 64) c2 = 64;
            int jj = nb + (lane < c2 ? lane : c2 - 1);
            r_rec = srec4[jj];
        }

        int nsub = (cnt64 + 15) >> 4;
        for (int i = 0; i < nsub; ++i) {
            // ---- ea stage via MFMA (K=4 in a 16x16x32) ----
            float4 q = edge4[i*16 + lo16];
            unsigned pa0 = cvt_pk_bf16(q.x, q.y);
            unsigned pa1 = cvt_pk_bf16(q.z, q.w);
            uint4 av = (hi == 0) ? (uint4){pa0, pa1, 0u, 0u}
                                 : (uint4){0u, 0u, 0u, 0u};
            s16x8 aea = *reinterpret_cast<s16x8*>(&av);
            #pragma unroll
            for (int t2 = 0; t2 < 4; ++t2) {
                f32x4 pre = {0.f, 0.f, 0.f, 0.f};
                pre = __builtin_amdgcn_mfma_f32_16x16x32_bf16(aea, wfe[t2], pre, 0, 0, 0);
                #pragma unroll
                for (int r = 0; r < 4; ++r)
                    ealds[(hi*4+r)*72 + t2*16 + lo16] =
                        (unsigned short)cvt_pk_bf16(silu_f(pre[r]), 0.f);
            }
            const unsigned short* arow = ealds + lo16*72 + hi*8;
            s16x8 a0 = *(const s16x8*)(arow);
            s16x8 a1 = *(const s16x8*)(arow + 32);

            // ---- msg MFMAs; D output = V-MFMA B-frags (registers) ----
            s16x4 Bf[4];
            #pragma unroll
            for (int t2 = 0; t2 < 4; ++t2) {
                const float bvt = bv4[t2];
                f32x4 am = {bvt, bvt, bvt, bvt};
                am = __builtin_amdgcn_mfma_f32_16x16x32_bf16(a0, bfr[t2][0], am, 0, 0, 0);
                am = __builtin_amdgcn_mfma_f32_16x16x32_bf16(a1, bfr[t2][1], am, 0, 0, 0);
                unsigned u0 = cvt_pk_bf16(silu_f(am[0]), silu_f(am[1]));
                unsigned u1 = cvt_pk_bf16(silu_f(am[2]), silu_f(am[3]));
                union { uint2 u2; s16x4 s4; } cv;
                cv.u2 = (uint2){u0, u1};
                Bf[t2] = cv.s4;
            }

            // ---- ONE V+agg MFMA per ch-tile: all 4 nodes at once ----
            s16x4 a_ev = *(const s16x4*)(evT + lo16*72 + i*16 + hi*4);
            acc[0] = MFMA16(a_ev, Bf[0], acc[0]);
            acc[1] = MFMA16(a_ev, Bf[1], acc[1]);
            acc[2] = MFMA16(a_ev, Bf[2], acc[2]);
            acc[3] = MFMA16(a_ev, Bf[3], acc[3]);
        }
        ebase = nb;
        cnt64 = eend - ebase; if (cnt64 > 64) cnt64 = 64;
    }

    // ---- dump: lane quarter hi owns node hi; regs {0,1,2}=v_xyz, 3=agg ----
    float npadv = hi==0 ? (float)npad[0] : hi==1 ? (float)npad[1]
                : hi==2 ? (float)npad[2] : (float)npad[3];
    #pragma unroll
    for (int t2 = 0; t2 < 4; ++t2) {
        float sbv = bf16f((unsigned short)cvt_pk_bf16(silu_f(bv4[t2]), 0.f));
        float ag  = acc[t2][3] - npadv * sbv;
        agg_l[hi*72 + t2*16 + lo16]       = (unsigned short)cvt_pk_bf16(ag, ag);
        v_l[(hi*3+0)*64 + t2*16 + lo16]   = (unsigned short)cvt_pk_bf16(acc[t2][0], 0.f);
        v_l[(hi*3+1)*64 + t2*16 + lo16]   = (unsigned short)cvt_pk_bf16(acc[t2][1], 0.f);
        v_l[(hi*3+2)*64 + t2*16 + lo16]   = (unsigned short)cvt_pk_bf16(acc[t2][2], 0.f);
    }
    wsync();

    // ---- node phase: gate = silu(h + silu(agg@Wu)) * wdec; out = vm * (v . gate) ----
    s16x8 wub[4][2];
    #pragma unroll
    for (int t2 = 0; t2 < 4; ++t2)
        #pragma unroll
        for (int s = 0; s < 2; ++s)
            wub[t2][s] = *(const s16x8*)(wfrag + 4096 + ((t2*2+s)*64 + lane)*8);
    const float tb = sb ? tarr[1] : tarr[0];
    float hb4[4], wd4[4];
    #pragma unroll
    for (int t2 = 0; t2 < 4; ++t2) {
        hb4[t2] = Wsp[t2*16+lo16] + tb * Wt[t2*16+lo16];
        wd4[t2] = wdec[t2*16+lo16];
    }
    s16x8 ga0 = *(const s16x8*)(agg_l + lo16*72 + hi*8);   // rows>=4 garbage, guarded
    s16x8 ga1 = *(const s16x8*)(agg_l + lo16*72 + hi*8 + 32);
    float p[4][3] = {{0.f,0.f,0.f},{0.f,0.f,0.f},{0.f,0.f,0.f},{0.f,0.f,0.f}};
    #pragma unroll
    for (int t2 = 0; t2 < 4; ++t2) {
        f32x4 accg = {0.f, 0.f, 0.f, 0.f};
        accg = __builtin_amdgcn_mfma_f32_16x16x32_bf16(ga0, wub[t2][0], accg, 0, 0, 0);
        accg = __builtin_amdgcn_mfma_f32_16x16x32_bf16(ga1, wub[t2][1], accg, 0, 0, 0);
        #pragma unroll
        for (int r = 0; r < 4; ++r) {
            int node = hi*4 + r;
            float hn   = hb4[t2] + silu_f(accg[r]);
            float gate = silu_f(hn) * wd4[t2];
            if (node < 4) {
                #pragma unroll
                for (int c = 0; c < 3; ++c) {
                    float vv = bf16f(v_l[(node*3+c)*64 + t2*16 + lo16]);
                    p[r][c] = fmaf(gate, vv, p[r][c]);
                }
            }
        }
    }
    #pragma unroll
    for (int st = 1; st < 16; st <<= 1)
        #pragma unroll
        for (int r = 0; r < 4; ++r)
            #pragma unroll
            for (int c = 0; c < 3; ++c)
                p[r][c] += __shfl_xor(p[r][c], st, 64);

    if (lo16 < 12 && hi == 0) {
        int rr = lo16 / 3, c = lo16 - rr*3;
        float val = rr==0 ? (c==0 ? p[0][0] : c==1 ? p[0][1] : p[0][2])
                  : rr==1 ? (c==0 ? p[1][0] : c==1 ? p[1][1] : p[1][2])
                  : rr==2 ? (c==0 ? p[2][0] : c==1 ? p[2][1] : p[2][2])
                  :         (c==0 ? p[3][0] : c==1 ? p[3][1] : p[3][2]);
        out[(n0 + rr)*3 + c] = val * vm[n0 + rr];
    }
}

extern "C" void kernel_launch(void* const* d_in, const int* in_sizes, int n_in,
                              void* d_out, int out_size, void* d_ws, size_t ws_size,
                              hipStream_t stream) {
    const float* x    = (const float*)d_in[0];
    const float* t    = (const float*)d_in[1];
    const float* cell = (const float*)d_in[2];
    const float* x1   = (const float*)d_in[3];
    const float* vm   = (const float*)d_in[4];
    const float* Wsp  = (const float*)d_in[5];
    const float* Wt   = (const float*)d_in[6];
    const float* We   = (const float*)d_in[7];
    const float* Wm   = (const float*)d_in[8];
    const float* Wu   = (const float*)d_in[9];
    const float* wdec = (const float*)d_in[10];
    const int*   ei   = (const int*)d_in[11];
    const int*   tj   = (const int*)d_in[12];
    float* out = (float*)d_out;

    // ws layout (float units):
    float*  ws      = (float*)d_ws;
    float4* srec4   = (float4*)ws;                       // [622592] f4
    float*  pos     = ws + 2490368;                      // [98304]
    int*    rank    = (int*)(pos + 98304);               // [524288]
    int*    rowptr  = rank + 524288;                     // [32772 pad]
    int*    rowptr4 = rowptr + 32772;                    // [8*RP4S = 32800]
    int*    cnt     = rowptr4 + 32800;                   // [32768]
    float*  base_ws = (float*)(cnt + 32768);             // [128]
    unsigned short* wfrag = (unsigned short*)(base_ws + 128);  // [10240]

    hipMemsetAsync(cnt, 0, 32768*sizeof(int), stream);
    k_prep_hist_base<<<2057, 256, 0, stream>>>(x, x1, vm, pos, ei, cnt, rank,
                                               Wsp, Wt, Wm, Wu, We, t, base_ws, wfrag);
    k_scan<<<8, 1024, 0, stream>>>(cnt, rowptr, rowptr4);
    k_sortgeo<<<2176, 256, 0, stream>>>(ei, tj, pos, cell, rowptr, rowptr4, rank, srec4);
    k_edge_all<<<8192, 64, 0, stream>>>(srec4, rowptr, rowptr4, wfrag, base_ws,
                                        Wsp, Wt, wdec, t, vm, out);
}

// Round 21
// 79.758 us; speedup vs baseline: 1.1692x; 1.0268x over previous
//
#include <hip/hip_runtime.h>
#include <math.h>

#define NNODE 32768     // B*T*N
#define NEDGE 524288    // NNODE * DEG
#define DD 64           // feature dim D
#define SSTRIDE 77824   // padded slot stride per structure
#define RP4S 4100       // rowptr4 row stride per structure

typedef float  f32x4 __attribute__((ext_vector_type(4)));
typedef short  s16x8 __attribute__((ext_vector_type(8)));
typedef short  s16x4 __attribute__((ext_vector_type(4)));

__device__ __forceinline__ float silu_f(float x) {
    return x * __builtin_amdgcn_rcpf(1.0f + __expf(-x));
}
__device__ __forceinline__ unsigned cvt_pk_bf16(float a, float b) {
    unsigned r;
    asm("v_cvt_pk_bf16_f32 %0, %1, %2" : "=v"(r) : "v"(a), "v"(b));
    return r;   // [15:0]=bf16(a), [31:16]=bf16(b), RNE
}
__device__ __forceinline__ unsigned short bf16r(float f) {
    unsigned u = __float_as_uint(f);
    unsigned r = (u + 0x7FFFu + ((u >> 16) & 1u)) >> 16;
    return (unsigned short)r;
}
__device__ __forceinline__ float bf16f(unsigned short u) {
    return __uint_as_float(((unsigned)u) << 16);
}
__device__ __forceinline__ void wsync() {
    asm volatile("s_waitcnt lgkmcnt(0)" ::: "memory");
    __builtin_amdgcn_sched_barrier(0);
}

// 16x16x16 bf16 MFMA (K=16)
#if defined(__has_builtin) && __has_builtin(__builtin_amdgcn_mfma_f32_16x16x16bf16_1k)
#define MFMA16(a,b,c) __builtin_amdgcn_mfma_f32_16x16x16bf16_1k((a),(b),(c),0,0,0)
#else
__device__ __forceinline__ f32x4 mfma16_asm(s16x4 a, s16x4 b, f32x4 c) {
    asm("v_mfma_f32_16x16x16_bf16 %0, %1, %2, %0" : "+v"(c) : "v"(a), "v"(b));
    return c;
}
#define MFMA16(a,b,c) mfma16_asm((a),(b),(c))
#endif

// fused: pos prep (0..127) + XCD-swizzled dst histogram/rank (0..2047)
//        + wfrag (2048..2055) + base (2056)
__global__ __launch_bounds__(256) void k_prep_hist_base(
    const float* __restrict__ x, const float* __restrict__ x1,
    const float* __restrict__ vm, float* __restrict__ pos,
    const int* __restrict__ ei, int* __restrict__ cnt, int* __restrict__ rank,
    const float* __restrict__ Wsp, const float* __restrict__ Wt,
    const float* __restrict__ Wm, const float* __restrict__ Wu,
    const float* __restrict__ We, const float* __restrict__ tarr,
    float* __restrict__ base_ws, unsigned short* __restrict__ wfrag)
{
    int tid = threadIdx.x, b = blockIdx.x;
    if (b >= 2048) {
        if (b < 2056) {
            #pragma unroll
            for (int j = 0; j < 5; ++j) {
                int idx = (b - 2048) * 1280 + j * 256 + tid;
                unsigned short v;
                if (idx < 8192) {
                    int sel = idx >> 12, id2 = idx & 4095;
                    int jj = id2 & 7;
                    int ln = (id2 >> 3) & 63;
                    int ts = id2 >> 9;
                    int t2 = ts >> 1, s = ts & 1;
                    int k   = s*32 + (ln >> 4)*8 + jj;
                    int col = t2*16 + (ln & 15);
                    v = bf16r(sel ? Wu[k*DD + col] : Wm[(128 + k)*DD + col]);
                } else {
                    int id3 = idx - 8192;
                    int jj = id3 & 7, ln = (id3 >> 3) & 63, t2 = id3 >> 9;
                    v = (ln < 16 && jj < 4) ? bf16r(We[jj*DD + t2*16 + (ln & 15)])
                                            : (unsigned short)0;
                }
                wfrag[idx] = v;
            }
        } else if (tid < 64) {
            float t0 = tarr[0], t1 = tarr[1];
            float aA = 0.0f, aB = 0.0f;
            #pragma unroll 8
            for (int k = 0; k < DD; ++k) {
                float w = Wm[k*DD + tid] + Wm[(DD+k)*DD + tid];
                aA = fmaf(Wsp[k] + t0*Wt[k], w, aA);
                aB = fmaf(Wsp[k] + t1*Wt[k], w, aB);
            }
            base_ws[tid]      = aA;
            base_ws[DD + tid] = aB;
        }
        return;
    }
    if (b < 128) {
        int i = b*256 + tid;
        float m = vm[i];
        #pragma unroll
        for (int c = 0; c < 3; ++c)
            pos[i*3+c] = x[i*3+c]*m + x1[i*3+c]*(1.0f-m);
    }
    int e = (b & 7) * 65536 + (b >> 3) * 256 + tid;
    rank[e] = atomicAdd(&cnt[ei[NEDGE + e]], 1);
}

// per-structure dual exclusive scan: rowptr (real) + rowptr4 (x4-padded)
__global__ __launch_bounds__(1024) void k_scan(
    const int* __restrict__ cnt, int* __restrict__ rowptr, int* __restrict__ rowptr4)
{
    __shared__ int buf[2][1024];
    const int g = blockIdx.x;          // 8 blocks
    const int tid = threadIdx.x;
    int4 L = ((const int4*)cnt)[g*1024 + tid];
    int s = L.x + L.y + L.z + L.w;
    buf[0][tid] = s;
    __syncthreads();
    int pp = 0;
    for (int off = 1; off < 1024; off <<= 1) {
        int v = buf[pp][tid];
        if (tid >= off) v += buf[pp][tid - off];
        buf[pp^1][tid] = v;
        __syncthreads();
        pp ^= 1;
    }
    int ex = (tid ? buf[pp][tid-1] : 0) + g*65536;
    int4 o;
    o.x = ex; ex += L.x;
    o.y = ex; ex += L.y;
    o.z = ex; ex += L.z;
    o.w = ex; ex += L.w;
    ((int4*)rowptr)[g*1024 + tid] = o;
    if (g == 7 && tid == 1023) rowptr[32768] = NEDGE;
    __syncthreads();
    int4 P = { (L.x+3)&~3, (L.y+3)&~3, (L.z+3)&~3, (L.w+3)&~3 };
    int s4 = P.x + P.y + P.z + P.w;
    buf[0][tid] = s4;
    __syncthreads();
    pp = 0;
    for (int off = 1; off < 1024; off <<= 1) {
        int v = buf[pp][tid];
        if (tid >= off) v += buf[pp][tid - off];
        buf[pp^1][tid] = v;
        __syncthreads();
        pp ^= 1;
    }
    int ex4 = (tid ? buf[pp][tid-1] : 0) + g*SSTRIDE;
    int4 o4;
    o4.x = ex4; ex4 += P.x;
    o4.y = ex4; ex4 += P.y;
    o4.z = ex4; ex4 += P.z;
    o4.w = ex4; ex4 += P.w;
    *(int4*)(rowptr4 + g*RP4S + tid*4) = o4;
    if (tid == 1023) rowptr4[g*RP4S + 4096] = ex4;
}

// geometry + counting-sort scatter into bf16-packed padded slots
// (blocks 0..2047, XCD-swizzled) + pad-slot zeroing (blocks 2048..2175)
__global__ __launch_bounds__(256) void k_sortgeo(
    const int* __restrict__ ei, const int* __restrict__ tj,
    const float* __restrict__ pos, const float* __restrict__ cell,
    const int* __restrict__ rowptr, const int* __restrict__ rowptr4,
    const int* __restrict__ rank, uint2* __restrict__ srec4)
{
    int b = blockIdx.x;
    if (b >= 2048) {
        int n  = (b - 2048) * 256 + threadIdx.x;     // node 0..32767
        int g  = n >> 12;
        int li = g*RP4S + (n & 4095);
        int s0 = rowptr4[li];
        int s1 = rowptr4[li + 1];
        int deg = rowptr[n + 1] - rowptr[n];
        for (int s = s0 + deg; s < s1; ++s)
            srec4[s] = (uint2){0u, 0u};
        return;
    }
    int e = (b & 7) * 65536 + (b >> 3) * 256 + threadIdx.x;
    int g = b & 7;
    int src = ei[e];
    int dst = ei[NEDGE + e];
    const float* cl = cell + g*9;
    float c00=cl[0],c01=cl[1],c02=cl[2],c10=cl[3],c11=cl[4],c12=cl[5],c20=cl[6],c21=cl[7],c22=cl[8];
    float tj0 = (float)tj[e*3+0], tj1 = (float)tj[e*3+1], tj2 = (float)tj[e*3+2];
    float ev0 = pos[dst*3+0] - pos[src*3+0] + tj0*c00 + tj1*c10 + tj2*c20;
    float ev1 = pos[dst*3+1] - pos[src*3+1] + tj0*c01 + tj1*c11 + tj2*c21;
    float ev2 = pos[dst*3+2] - pos[src*3+2] + tj0*c02 + tj1*c12 + tj2*c22;
    float len = sqrtf(ev0*ev0 + ev1*ev1 + ev2*ev2 + 1e-12f);
    int slot = rowptr4[g*RP4S + (dst & 4095)] + rank[e];
    srec4[slot] = (uint2){cvt_pk_bf16(ev0, ev1), cvt_pk_bf16(ev2, len)};
}

// One wave per 4-node group (8192 blocks). x4-padded CSR, bf16-packed records.
// Masked evT A-tile (row 4n+r = ev_r of node n's columns); ONE 16x16x16 MFMA
// per ch-tile per subtile computes v(x,y,z)+agg for all 4 nodes.
__global__ __launch_bounds__(64) void k_edge_all(
    const uint2* __restrict__ srec4,
    const int* __restrict__ rowptr, const int* __restrict__ rowptr4,
    const unsigned short* __restrict__ wfrag,
    const float* __restrict__ base_ws,
    const float* __restrict__ Wsp, const float* __restrict__ Wt,
    const float* __restrict__ wdec, const float* __restrict__ tarr,
    const float* __restrict__ vm, float* __restrict__ out)
{
    const int lane = threadIdx.x;
    const int lo16 = lane & 15;
    const int hi   = lane >> 4;
    const int grp  = (blockIdx.x & 7) * 1024 + (blockIdx.x >> 3);  // XCD slice
    const int n0   = grp * 4;

    // LDS 7424 B:
    // @0 edge4 uint2[64] (512) | @512 evT u16[16][72] (2304) | @2816 ealds u16[16][72] (2304)
    // @5120 agg_l u16[4][72] (576) | @5696 v_l u16[12][64] (1536) | pad to 7424 (A-read overrun)
    __shared__ __align__(16) char my[7424];
    uint2*          edge4 = (uint2*)my;
    unsigned short* evT   = (unsigned short*)(my + 512);
    unsigned short* ealds = (unsigned short*)(my + 2816);
    unsigned short* agg_l = (unsigned short*)(my + 5120);
    unsigned short* v_l   = (unsigned short*)(my + 5696);

    // accumulators: acc[t2][reg] — lane quarter hi = node hi, reg = {x,y,z,agg}
    f32x4 acc[4] = {};

    // weights
    s16x8 bfr[4][2], wfe[4];
    #pragma unroll
    for (int t2 = 0; t2 < 4; ++t2) {
        #pragma unroll
        for (int s = 0; s < 2; ++s)
            bfr[t2][s] = *(const s16x8*)(wfrag + ((t2*2+s)*64 + lane)*8);
        wfe[t2] = *(const s16x8*)(wfrag + 8192 + (t2*64 + lane)*8);
    }
    const bool  sb  = (n0 >> 14) != 0;         // batch
    float bv4[4];
    #pragma unroll
    for (int t2 = 0; t2 < 4; ++t2)
        bv4[t2] = base_ws[(sb ? DD : 0) + t2*16 + lo16];

    // scalar CSR bounds (padded + real)
    const int gS = n0 >> 12;
    const int li = gS*RP4S + (n0 & 4095);
    int rp4a[5], npad[4];
    #pragma unroll
    for (int k = 0; k <= 4; ++k)
        rp4a[k] = __builtin_amdgcn_readfirstlane(rowptr4[li + k]);
    #pragma unroll
    for (int k = 0; k < 4; ++k) {
        int r0 = __builtin_amdgcn_readfirstlane(rowptr[n0 + k]);
        int r1 = __builtin_amdgcn_readfirstlane(rowptr[n0 + k + 1]);
        npad[k] = (rp4a[k+1] - rp4a[k]) - (r1 - r0);
    }

    const int estart = rp4a[0];
    const int eend   = rp4a[4];

    int ebase = estart;
    int cnt64 = eend - ebase; if (cnt64 > 64) cnt64 = 64;
    uint2 r_rec = {0u, 0u};
    if (ebase < eend) {
        int ii = ebase + (lane < cnt64 ? lane : cnt64 - 1);
        r_rec = srec4[ii];
    }

    while (ebase < eend) {
        uint2 cur = r_rec;
        edge4[lane] = cur;
        // masked evT: zero 16 rows, then scatter this lane's node rows (bit-extract)
        {
            int* ez = (int*)evT;
            #pragma unroll
            for (int j = 0; j < 9; ++j) ez[j*64 + lane] = 0;
        }
        if (lane < cnt64) {
            int slot = ebase + lane;
            int nd = (slot >= rp4a[1]) + (slot >= rp4a[2]) + (slot >= rp4a[3]);
            evT[(nd*4+0)*72 + lane] = (unsigned short)(cur.x & 0xffffu);
            evT[(nd*4+1)*72 + lane] = (unsigned short)(cur.x >> 16);
            evT[(nd*4+2)*72 + lane] = (unsigned short)(cur.y & 0xffffu);
            evT[(nd*4+3)*72 + lane] = 0x3F80;   // 1.0 -> agg row
        }

        // prefetch next window
        int nb = ebase + 64;
        if (nb < eend) {
            int c2 = eend - nb; if (c2 > 64) c2 = 64;
            int jj = nb + (lane < c2 ? lane : c2 - 1);
            r_rec = srec4[jj];
        }

        int nsub = (cnt64 + 15) >> 4;
        for (int i = 0; i < nsub; ++i) {
            // ---- ea stage via MFMA (K=4 in a 16x16x32); A = raw packed record ----
            uint2 qq = edge4[i*16 + lo16];
            uint4 av = (hi == 0) ? (uint4){qq.x, qq.y, 0u, 0u}
                                 : (uint4){0u, 0u, 0u, 0u};
            s16x8 aea = *reinterpret_cast<s16x8*>(&av);
            #pragma unroll
            for (int t2 = 0; t2 < 4; ++t2) {
                f32x4 pre = {0.f, 0.f, 0.f, 0.f};
                pre = __builtin_amdgcn_mfma_f32_16x16x32_bf16(aea, wfe[t2], pre, 0, 0, 0);
                #pragma unroll
                for (int r = 0; r < 4; ++r)
                    ealds[(hi*4+r)*72 + t2*16 + lo16] =
                        (unsigned short)cvt_pk_bf16(silu_f(pre[r]), 0.f);
            }
            const unsigned short* arow = ealds + lo16*72 + hi*8;
            s16x8 a0 = *(const s16x8*)(arow);
            s16x8 a1 = *(const s16x8*)(arow + 32);

            // ---- msg MFMAs; D output = V-MFMA B-frags (registers) ----
            s16x4 Bf[4];
            #pragma unroll
            for (int t2 = 0; t2 < 4; ++t2) {
                const float bvt = bv4[t2];
                f32x4 am = {bvt, bvt, bvt, bvt};
                am = __builtin_amdgcn_mfma_f32_16x16x32_bf16(a0, bfr[t2][0], am, 0, 0, 0);
                am = __builtin_amdgcn_mfma_f32_16x16x32_bf16(a1, bfr[t2][1], am, 0, 0, 0);
                unsigned u0 = cvt_pk_bf16(silu_f(am[0]), silu_f(am[1]));
                unsigned u1 = cvt_pk_bf16(silu_f(am[2]), silu_f(am[3]));
                union { uint2 u2; s16x4 s4; } cv;
                cv.u2 = (uint2){u0, u1};
                Bf[t2] = cv.s4;
            }

            // ---- ONE V+agg MFMA per ch-tile: all 4 nodes at once ----
            s16x4 a_ev = *(const s16x4*)(evT + lo16*72 + i*16 + hi*4);
            acc[0] = MFMA16(a_ev, Bf[0], acc[0]);
            acc[1] = MFMA16(a_ev, Bf[1], acc[1]);
            acc[2] = MFMA16(a_ev, Bf[2], acc[2]);
            acc[3] = MFMA16(a_ev, Bf[3], acc[3]);
        }
        ebase = nb;
        cnt64 = eend - ebase; if (cnt64 > 64) cnt64 = 64;
    }

    // ---- dump: lane quarter hi owns node hi; regs {0,1,2}=v_xyz, 3=agg ----
    float npadv = hi==0 ? (float)npad[0] : hi==1 ? (float)npad[1]
                : hi==2 ? (float)npad[2] : (float)npad[3];
    #pragma unroll
    for (int t2 = 0; t2 < 4; ++t2) {
        float sbv = bf16f((unsigned short)cvt_pk_bf16(silu_f(bv4[t2]), 0.f));
        float ag  = acc[t2][3] - npadv * sbv;
        agg_l[hi*72 + t2*16 + lo16]       = (unsigned short)cvt_pk_bf16(ag, ag);
        v_l[(hi*3+0)*64 + t2*16 + lo16]   = (unsigned short)cvt_pk_bf16(acc[t2][0], 0.f);
        v_l[(hi*3+1)*64 + t2*16 + lo16]   = (unsigned short)cvt_pk_bf16(acc[t2][1], 0.f);
        v_l[(hi*3+2)*64 + t2*16 + lo16]   = (unsigned short)cvt_pk_bf16(acc[t2][2], 0.f);
    }
    wsync();

    // ---- node phase: gate = silu(h + silu(agg@Wu)) * wdec; out = vm * (v . gate) ----
    s16x8 wub[4][2];
    #pragma unroll
    for (int t2 = 0; t2 < 4; ++t2)
        #pragma unroll
        for (int s = 0; s < 2; ++s)
            wub[t2][s] = *(const s16x8*)(wfrag + 4096 + ((t2*2+s)*64 + lane)*8);
    const float tb = sb ? tarr[1] : tarr[0];
    float hb4[4], wd4[4];
    #pragma unroll
    for (int t2 = 0; t2 < 4; ++t2) {
        hb4[t2] = Wsp[t2*16+lo16] + tb * Wt[t2*16+lo16];
        wd4[t2] = wdec[t2*16+lo16];
    }
    s16x8 ga0 = *(const s16x8*)(agg_l + lo16*72 + hi*8);   // rows>=4 garbage, guarded
    s16x8 ga1 = *(const s16x8*)(agg_l + lo16*72 + hi*8 + 32);
    float p[4][3] = {{0.f,0.f,0.f},{0.f,0.f,0.f},{0.f,0.f,0.f},{0.f,0.f,0.f}};
    #pragma unroll
    for (int t2 = 0; t2 < 4; ++t2) {
        f32x4 accg = {0.f, 0.f, 0.f, 0.f};
        accg = __builtin_amdgcn_mfma_f32_16x16x32_bf16(ga0, wub[t2][0], accg, 0, 0, 0);
        accg = __builtin_amdgcn_mfma_f32_16x16x32_bf16(ga1, wub[t2][1], accg, 0, 0, 0);
        #pragma unroll
        for (int r = 0; r < 4; ++r) {
            int node = hi*4 + r;
            float hn   = hb4[t2] + silu_f(accg[r]);
            float gate = silu_f(hn) * wd4[t2];
            if (node < 4) {
                #pragma unroll
                for (int c = 0; c < 3; ++c) {
                    float vv = bf16f(v_l[(node*3+c)*64 + t2*16 + lo16]);
                    p[r][c] = fmaf(gate, vv, p[r][c]);
                }
            }
        }
    }
    #pragma unroll
    for (int st = 1; st < 16; st <<= 1)
        #pragma unroll
        for (int r = 0; r < 4; ++r)
            #pragma unroll
            for (int c = 0; c < 3; ++c)
                p[r][c] += __shfl_xor(p[r][c], st, 64);

    if (lo16 < 12 && hi == 0) {
        int rr = lo16 / 3, c = lo16 - rr*3;
        float val = rr==0 ? (c==0 ? p[0][0] : c==1 ? p[0][1] : p[0][2])
                  : rr==1 ? (c==0 ? p[1][0] : c==1 ? p[1][1] : p[1][2])
                  : rr==2 ? (c==0 ? p[2][0] : c==1 ? p[2][1] : p[2][2])
                  :         (c==0 ? p[3][0] : c==1 ? p[3][1] : p[3][2]);
        out[(n0 + rr)*3 + c] = val * vm[n0 + rr];
    }
}

extern "C" void kernel_launch(void* const* d_in, const int* in_sizes, int n_in,
                              void* d_out, int out_size, void* d_ws, size_t ws_size,
                              hipStream_t stream) {
    const float* x    = (const float*)d_in[0];
    const float* t    = (const float*)d_in[1];
    const float* cell = (const float*)d_in[2];
    const float* x1   = (const float*)d_in[3];
    const float* vm   = (const float*)d_in[4];
    const float* Wsp  = (const float*)d_in[5];
    const float* Wt   = (const float*)d_in[6];
    const float* We   = (const float*)d_in[7];
    const float* Wm   = (const float*)d_in[8];
    const float* Wu   = (const float*)d_in[9];
    const float* wdec = (const float*)d_in[10];
    const int*   ei   = (const int*)d_in[11];
    const int*   tj   = (const int*)d_in[12];
    float* out = (float*)d_out;

    // ws layout (float units):
    float*  ws      = (float*)d_ws;
    uint2*  srec4   = (uint2*)ws;                        // [622592] uint2 = 1245184 f
    float*  pos     = ws + 1245184;                      // [98304]
    int*    rank    = (int*)(pos + 98304);               // [524288]
    int*    rowptr  = rank + 524288;                     // [32772 pad]
    int*    rowptr4 = rowptr + 32772;                    // [8*RP4S = 32800]
    int*    cnt     = rowptr4 + 32800;                   // [32768]
    float*  base_ws = (float*)(cnt + 32768);             // [128]
    unsigned short* wfrag = (unsigned short*)(base_ws + 128);  // [10240]

    hipMemsetAsync(cnt, 0, 32768*sizeof(int), stream);
    k_prep_hist_base<<<2057, 256, 0, stream>>>(x, x1, vm, pos, ei, cnt, rank,
                                               Wsp, Wt, Wm, Wu, We, t, base_ws, wfrag);
    k_scan<<<8, 1024, 0, stream>>>(cnt, rowptr, rowptr4);
    k_sortgeo<<<2176, 256, 0, stream>>>(ei, tj, pos, cell, rowptr, rowptr4, rank, srec4);
    k_edge_all<<<8192, 64, 0, stream>>>(srec4, rowptr, rowptr4, wfrag, base_ws,
                                        Wsp, Wt, wdec, t, vm, out);
}

// Round 23
// 79.288 us; speedup vs baseline: 1.1762x; 1.0059x over previous
//
#include <hip/hip_runtime.h>
#include <math.h>

#define NNODE 32768     // B*T*N
#define NEDGE 524288    // NNODE * DEG
#define DD 64           // feature dim D
#define SSTRIDE 77824   // padded slot stride per structure
#define RP4S 4100       // rowptr4 row stride per structure

typedef float  f32x4 __attribute__((ext_vector_type(4)));
typedef short  s16x8 __attribute__((ext_vector_type(8)));
typedef short  s16x4 __attribute__((ext_vector_type(4)));

__device__ __forceinline__ float silu_f(float x) {
    return x * __builtin_amdgcn_rcpf(1.0f + __expf(-x));
}
__device__ __forceinline__ unsigned cvt_pk_bf16(float a, float b) {
    unsigned r;
    asm("v_cvt_pk_bf16_f32 %0, %1, %2" : "=v"(r) : "v"(a), "v"(b));
    return r;   // [15:0]=bf16(a), [31:16]=bf16(b), RNE
}
__device__ __forceinline__ unsigned short bf16r(float f) {
    unsigned u = __float_as_uint(f);
    unsigned r = (u + 0x7FFFu + ((u >> 16) & 1u)) >> 16;
    return (unsigned short)r;
}
__device__ __forceinline__ float bf16f(unsigned short u) {
    return __uint_as_float(((unsigned)u) << 16);
}
__device__ __forceinline__ void wsync() {
    asm volatile("s_waitcnt lgkmcnt(0)" ::: "memory");
    __builtin_amdgcn_sched_barrier(0);
}

// 16x16x16 bf16 MFMA (K=16)
#if defined(__has_builtin) && __has_builtin(__builtin_amdgcn_mfma_f32_16x16x16bf16_1k)
#define MFMA16(a,b,c) __builtin_amdgcn_mfma_f32_16x16x16bf16_1k((a),(b),(c),0,0,0)
#else
__device__ __forceinline__ f32x4 mfma16_asm(s16x4 a, s16x4 b, f32x4 c) {
    asm("v_mfma_f32_16x16x16_bf16 %0, %1, %2, %0" : "+v"(c) : "v"(a), "v"(b));
    return c;
}
#define MFMA16(a,b,c) mfma16_asm((a),(b),(c))
#endif

// fused: pos prep (0..127) + XCD-swizzled dst histogram/rank (0..2047)
//        + wfrag (2048..2055) + base (2056)
__global__ __launch_bounds__(256) void k_prep_hist_base(
    const float* __restrict__ x, const float* __restrict__ x1,
    const float* __restrict__ vm, float* __restrict__ pos,
    const int* __restrict__ ei, int* __restrict__ cnt, unsigned short* __restrict__ rank,
    const float* __restrict__ Wsp, const float* __restrict__ Wt,
    const float* __restrict__ Wm, const float* __restrict__ Wu,
    const float* __restrict__ We, const float* __restrict__ tarr,
    float* __restrict__ base_ws, unsigned short* __restrict__ wfrag)
{
    int tid = threadIdx.x, b = blockIdx.x;
    if (b >= 2048) {
        if (b < 2056) {
            #pragma unroll
            for (int j = 0; j < 5; ++j) {
                int idx = (b - 2048) * 1280 + j * 256 + tid;
                unsigned short v;
                if (idx < 8192) {
                    int sel = idx >> 12, id2 = idx & 4095;
                    int jj = id2 & 7;
                    int ln = (id2 >> 3) & 63;
                    int ts = id2 >> 9;
                    int t2 = ts >> 1, s = ts & 1;
                    int k   = s*32 + (ln >> 4)*8 + jj;
                    int col = t2*16 + (ln & 15);
                    v = bf16r(sel ? Wu[k*DD + col] : Wm[(128 + k)*DD + col]);
                } else {
                    int id3 = idx - 8192;
                    int jj = id3 & 7, ln = (id3 >> 3) & 63, t2 = id3 >> 9;
                    v = (ln < 16 && jj < 4) ? bf16r(We[jj*DD + t2*16 + (ln & 15)])
                                            : (unsigned short)0;
                }
                wfrag[idx] = v;
            }
        } else if (tid < 64) {
            float t0 = tarr[0], t1 = tarr[1];
            float aA = 0.0f, aB = 0.0f;
            #pragma unroll 8
            for (int k = 0; k < DD; ++k) {
                float w = Wm[k*DD + tid] + Wm[(DD+k)*DD + tid];
                aA = fmaf(Wsp[k] + t0*Wt[k], w, aA);
                aB = fmaf(Wsp[k] + t1*Wt[k], w, aB);
            }
            base_ws[tid]      = aA;
            base_ws[DD + tid] = aB;
        }
        return;
    }
    if (b < 128) {
        int i = b*256 + tid;
        float m = vm[i];
        #pragma unroll
        for (int c = 0; c < 3; ++c)
            pos[i*3+c] = x[i*3+c]*m + x1[i*3+c]*(1.0f-m);
    }
    int e = (b & 7) * 65536 + (b >> 3) * 256 + tid;
    rank[e] = (unsigned short)atomicAdd(&cnt[ei[NEDGE + e]], 1);
}

// per-structure dual exclusive scan: rowptr (real) + rowptr4 (x4-padded)
__global__ __launch_bounds__(1024) void k_scan(
    const int* __restrict__ cnt, int* __restrict__ rowptr, int* __restrict__ rowptr4)
{
    __shared__ int buf[2][1024];
    const int g = blockIdx.x;          // 8 blocks
    const int tid = threadIdx.x;
    int4 L = ((const int4*)cnt)[g*1024 + tid];
    int s = L.x + L.y + L.z + L.w;
    buf[0][tid] = s;
    __syncthreads();
    int pp = 0;
    for (int off = 1; off < 1024; off <<= 1) {
        int v = buf[pp][tid];
        if (tid >= off) v += buf[pp][tid - off];
        buf[pp^1][tid] = v;
        __syncthreads();
        pp ^= 1;
    }
    int ex = (tid ? buf[pp][tid-1] : 0) + g*65536;
    int4 o;
    o.x = ex; ex += L.x;
    o.y = ex; ex += L.y;
    o.z = ex; ex += L.z;
    o.w = ex; ex += L.w;
    ((int4*)rowptr)[g*1024 + tid] = o;
    if (g == 7 && tid == 1023) rowptr[32768] = NEDGE;
    __syncthreads();
    int4 P = { (L.x+3)&~3, (L.y+3)&~3, (L.z+3)&~3, (L.w+3)&~3 };
    int s4 = P.x + P.y + P.z + P.w;
    buf[0][tid] = s4;
    __syncthreads();
    pp = 0;
    for (int off = 1; off < 1024; off <<= 1) {
        int v = buf[pp][tid];
        if (tid >= off) v += buf[pp][tid - off];
        buf[pp^1][tid] = v;
        __syncthreads();
        pp ^= 1;
    }
    int ex4 = (tid ? buf[pp][tid-1] : 0) + g*SSTRIDE;
    int4 o4;
    o4.x = ex4; ex4 += P.x;
    o4.y = ex4; ex4 += P.y;
    o4.z = ex4; ex4 += P.z;
    o4.w = ex4; ex4 += P.w;
    *(int4*)(rowptr4 + g*RP4S + tid*4) = o4;
    if (tid == 1023) rowptr4[g*RP4S + 4096] = ex4;
}

// geometry + counting-sort scatter into bf16-packed padded slots
// (blocks 0..2047, XCD-swizzled) + pad-slot zeroing (blocks 2048..2175)
__global__ __launch_bounds__(256) void k_sortgeo(
    const int* __restrict__ ei, const int* __restrict__ tj,
    const float* __restrict__ pos, const float* __restrict__ cell,
    const int* __restrict__ rowptr, const int* __restrict__ rowptr4,
    const unsigned short* __restrict__ rank, uint2* __restrict__ srec4)
{
    int b = blockIdx.x;
    if (b >= 2048) {
        int n  = (b - 2048) * 256 + threadIdx.x;     // node 0..32767
        int g  = n >> 12;
        int li = g*RP4S + (n & 4095);
        int s0 = rowptr4[li];
        int s1 = rowptr4[li + 1];
        int deg = rowptr[n + 1] - rowptr[n];
        for (int s = s0 + deg; s < s1; ++s)
            srec4[s] = (uint2){0u, 0u};
        return;
    }
    int e = (b & 7) * 65536 + (b >> 3) * 256 + threadIdx.x;
    int g = b & 7;
    int src = ei[e];
    int dst = ei[NEDGE + e];
    const float* cl = cell + g*9;
    float c00=cl[0],c01=cl[1],c02=cl[2],c10=cl[3],c11=cl[4],c12=cl[5],c20=cl[6],c21=cl[7],c22=cl[8];
    float tj0 = (float)tj[e*3+0], tj1 = (float)tj[e*3+1], tj2 = (float)tj[e*3+2];
    float ev0 = pos[dst*3+0] - pos[src*3+0] + tj0*c00 + tj1*c10 + tj2*c20;
    float ev1 = pos[dst*3+1] - pos[src*3+1] + tj0*c01 + tj1*c11 + tj2*c21;
    float ev2 = pos[dst*3+2] - pos[src*3+2] + tj0*c02 + tj1*c12 + tj2*c22;
    float len = sqrtf(ev0*ev0 + ev1*ev1 + ev2*ev2 + 1e-12f);
    int slot = rowptr4[g*RP4S + (dst & 4095)] + (int)rank[e];
    srec4[slot] = (uint2){cvt_pk_bf16(ev0, ev1), cvt_pk_bf16(ev2, len)};
}

// One wave per 4-node group (8192 blocks). x4-padded CSR, bf16-packed records.
// Masked evT A-tile (row 4n+r = ev_r of node n's columns); ONE 16x16x16 MFMA
// per ch-tile per subtile computes v(x,y,z)+agg for all 4 nodes.
// (r21 structure verbatim — full evT re-zero per window, single ealds buffer.)
__global__ __launch_bounds__(64) void k_edge_all(
    const uint2* __restrict__ srec4,
    const int* __restrict__ rowptr, const int* __restrict__ rowptr4,
    const unsigned short* __restrict__ wfrag,
    const float* __restrict__ base_ws,
    const float* __restrict__ Wsp, const float* __restrict__ Wt,
    const float* __restrict__ wdec, const float* __restrict__ tarr,
    const float* __restrict__ vm, float* __restrict__ out)
{
    const int lane = threadIdx.x;
    const int lo16 = lane & 15;
    const int hi   = lane >> 4;
    const int grp  = (blockIdx.x & 7) * 1024 + (blockIdx.x >> 3);  // XCD slice
    const int n0   = grp * 4;

    // LDS 7424 B:
    // @0 edge4 uint2[64] (512) | @512 evT u16[16][72] (2304) | @2816 ealds u16[16][72] (2304)
    // @5120 agg_l u16[4][72] (576) | @5696 v_l u16[12][64] (1536) | pad to 7424 (A-read overrun)
    __shared__ __align__(16) char my[7424];
    uint2*          edge4 = (uint2*)my;
    unsigned short* evT   = (unsigned short*)(my + 512);
    unsigned short* ealds = (unsigned short*)(my + 2816);
    unsigned short* agg_l = (unsigned short*)(my + 5120);
    unsigned short* v_l   = (unsigned short*)(my + 5696);

    // accumulators: acc[t2][reg] — lane quarter hi = node hi, reg = {x,y,z,agg}
    f32x4 acc[4] = {};

    // weights
    s16x8 bfr[4][2], wfe[4];
    #pragma unroll
    for (int t2 = 0; t2 < 4; ++t2) {
        #pragma unroll
        for (int s = 0; s < 2; ++s)
            bfr[t2][s] = *(const s16x8*)(wfrag + ((t2*2+s)*64 + lane)*8);
        wfe[t2] = *(const s16x8*)(wfrag + 8192 + (t2*64 + lane)*8);
    }
    const bool  sb  = (n0 >> 14) != 0;         // batch
    float bv4[4];
    #pragma unroll
    for (int t2 = 0; t2 < 4; ++t2)
        bv4[t2] = base_ws[(sb ? DD : 0) + t2*16 + lo16];

    // scalar CSR bounds (padded + real)
    const int gS = n0 >> 12;
    const int li = gS*RP4S + (n0 & 4095);
    int rp4a[5], npad[4];
    #pragma unroll
    for (int k = 0; k <= 4; ++k)
        rp4a[k] = __builtin_amdgcn_readfirstlane(rowptr4[li + k]);
    #pragma unroll
    for (int k = 0; k < 4; ++k) {
        int r0 = __builtin_amdgcn_readfirstlane(rowptr[n0 + k]);
        int r1 = __builtin_amdgcn_readfirstlane(rowptr[n0 + k + 1]);
        npad[k] = (rp4a[k+1] - rp4a[k]) - (r1 - r0);
    }

    const int estart = rp4a[0];
    const int eend   = rp4a[4];

    int ebase = estart;
    int cnt64 = eend - ebase; if (cnt64 > 64) cnt64 = 64;
    uint2 r_rec = {0u, 0u};
    if (ebase < eend) {
        int ii = ebase + (lane < cnt64 ? lane : cnt64 - 1);
        r_rec = srec4[ii];
    }

    while (ebase < eend) {
        uint2 cur = r_rec;
        edge4[lane] = cur;
        // masked evT: zero 16 rows, then scatter this lane's node rows (bit-extract)
        {
            int* ez = (int*)evT;
            #pragma unroll
            for (int j = 0; j < 9; ++j) ez[j*64 + lane] = 0;
        }
        if (lane < cnt64) {
            int slot = ebase + lane;
            int nd = (slot >= rp4a[1]) + (slot >= rp4a[2]) + (slot >= rp4a[3]);
            evT[(nd*4+0)*72 + lane] = (unsigned short)(cur.x & 0xffffu);
            evT[(nd*4+1)*72 + lane] = (unsigned short)(cur.x >> 16);
            evT[(nd*4+2)*72 + lane] = (unsigned short)(cur.y & 0xffffu);
            evT[(nd*4+3)*72 + lane] = 0x3F80;   // 1.0 -> agg row
        }

        // prefetch next window
        int nb = ebase + 64;
        if (nb < eend) {
            int c2 = eend - nb; if (c2 > 64) c2 = 64;
            int jj = nb + (lane < c2 ? lane : c2 - 1);
            r_rec = srec4[jj];
        }

        int nsub = (cnt64 + 15) >> 4;
        for (int i = 0; i < nsub; ++i) {
            // ---- ea stage via MFMA (K=4 in a 16x16x32); A = raw packed record ----
            uint2 qq = edge4[i*16 + lo16];
            uint4 av = (hi == 0) ? (uint4){qq.x, qq.y, 0u, 0u}
                                 : (uint4){0u, 0u, 0u, 0u};
            s16x8 aea = *reinterpret_cast<s16x8*>(&av);
            #pragma unroll
            for (int t2 = 0; t2 < 4; ++t2) {
                f32x4 pre = {0.f, 0.f, 0.f, 0.f};
                pre = __builtin_amdgcn_mfma_f32_16x16x32_bf16(aea, wfe[t2], pre, 0, 0, 0);
                #pragma unroll
                for (int r = 0; r < 4; ++r)
                    ealds[(hi*4+r)*72 + t2*16 + lo16] =
                        (unsigned short)cvt_pk_bf16(silu_f(pre[r]), 0.f);
            }
            const unsigned short* arow = ealds + lo16*72 + hi*8;
            s16x8 a0 = *(const s16x8*)(arow);
            s16x8 a1 = *(const s16x8*)(arow + 32);

            // ---- msg MFMAs; D output = V-MFMA B-frags (registers) ----
            s16x4 Bf[4];
            #pragma unroll
            for (int t2 = 0; t2 < 4; ++t2) {
                const float bvt = bv4[t2];
                f32x4 am = {bvt, bvt, bvt, bvt};
                am = __builtin_amdgcn_mfma_f32_16x16x32_bf16(a0, bfr[t2][0], am, 0, 0, 0);
                am = __builtin_amdgcn_mfma_f32_16x16x32_bf16(a1, bfr[t2][1], am, 0, 0, 0);
                unsigned u0 = cvt_pk_bf16(silu_f(am[0]), silu_f(am[1]));
                unsigned u1 = cvt_pk_bf16(silu_f(am[2]), silu_f(am[3]));
                union { uint2 u2; s16x4 s4; } cv;
                cv.u2 = (uint2){u0, u1};
                Bf[t2] = cv.s4;
            }

            // ---- ONE V+agg MFMA per ch-tile: all 4 nodes at once ----
            s16x4 a_ev = *(const s16x4*)(evT + lo16*72 + i*16 + hi*4);
            acc[0] = MFMA16(a_ev, Bf[0], acc[0]);
            acc[1] = MFMA16(a_ev, Bf[1], acc[1]);
            acc[2] = MFMA16(a_ev, Bf[2], acc[2]);
            acc[3] = MFMA16(a_ev, Bf[3], acc[3]);
        }
        ebase = nb;
        cnt64 = eend - ebase; if (cnt64 > 64) cnt64 = 64;
    }

    // ---- dump: lane quarter hi owns node hi; regs {0,1,2}=v_xyz, 3=agg ----
    float npadv = hi==0 ? (float)npad[0] : hi==1 ? (float)npad[1]
                : hi==2 ? (float)npad[2] : (float)npad[3];
    #pragma unroll
    for (int t2 = 0; t2 < 4; ++t2) {
        float sbv = bf16f((unsigned short)cvt_pk_bf16(silu_f(bv4[t2]), 0.f));
        float ag  = acc[t2][3] - npadv * sbv;
        agg_l[hi*72 + t2*16 + lo16]       = (unsigned short)cvt_pk_bf16(ag, ag);
        v_l[(hi*3+0)*64 + t2*16 + lo16]   = (unsigned short)cvt_pk_bf16(acc[t2][0], 0.f);
        v_l[(hi*3+1)*64 + t2*16 + lo16]   = (unsigned short)cvt_pk_bf16(acc[t2][1], 0.f);
        v_l[(hi*3+2)*64 + t2*16 + lo16]   = (unsigned short)cvt_pk_bf16(acc[t2][2], 0.f);
    }
    wsync();

    // ---- node phase: gate = silu(h + silu(agg@Wu)) * wdec; out = vm * (v . gate) ----
    s16x8 wub[4][2];
    #pragma unroll
    for (int t2 = 0; t2 < 4; ++t2)
        #pragma unroll
        for (int s = 0; s < 2; ++s)
            wub[t2][s] = *(const s16x8*)(wfrag + 4096 + ((t2*2+s)*64 + lane)*8);
    const float tb = sb ? tarr[1] : tarr[0];
    float hb4[4], wd4[4];
    #pragma unroll
    for (int t2 = 0; t2 < 4; ++t2) {
        hb4[t2] = Wsp[t2*16+lo16] + tb * Wt[t2*16+lo16];
        wd4[t2] = wdec[t2*16+lo16];
    }
    s16x8 ga0 = *(const s16x8*)(agg_l + lo16*72 + hi*8);   // rows>=4 garbage, guarded
    s16x8 ga1 = *(const s16x8*)(agg_l + lo16*72 + hi*8 + 32);
    float p[4][3] = {{0.f,0.f,0.f},{0.f,0.f,0.f},{0.f,0.f,0.f},{0.f,0.f,0.f}};
    #pragma unroll
    for (int t2 = 0; t2 < 4; ++t2) {
        f32x4 accg = {0.f, 0.f, 0.f, 0.f};
        accg = __builtin_amdgcn_mfma_f32_16x16x32_bf16(ga0, wub[t2][0], accg, 0, 0, 0);
        accg = __builtin_amdgcn_mfma_f32_16x16x32_bf16(ga1, wub[t2][1], accg, 0, 0, 0);
        #pragma unroll
        for (int r = 0; r < 4; ++r) {
            int node = hi*4 + r;
            float hn   = hb4[t2] + silu_f(accg[r]);
            float gate = silu_f(hn) * wd4[t2];
            if (node < 4) {
                #pragma unroll
                for (int c = 0; c < 3; ++c) {
                    float vv = bf16f(v_l[(node*3+c)*64 + t2*16 + lo16]);
                    p[r][c] = fmaf(gate, vv, p[r][c]);
                }
            }
        }
    }
    #pragma unroll
    for (int st = 1; st < 16; st <<= 1)
        #pragma unroll
        for (int r = 0; r < 4; ++r)
            #pragma unroll
            for (int c = 0; c < 3; ++c)
                p[r][c] += __shfl_xor(p[r][c], st, 64);

    if (lo16 < 12 && hi == 0) {
        int rr = lo16 / 3, c = lo16 - rr*3;
        float val = rr==0 ? (c==0 ? p[0][0] : c==1 ? p[0][1] : p[0][2])
                  : rr==1 ? (c==0 ? p[1][0] : c==1 ? p[1][1] : p[1][2])
                  : rr==2 ? (c==0 ? p[2][0] : c==1 ? p[2][1] : p[2][2])
                  :         (c==0 ? p[3][0] : c==1 ? p[3][1] : p[3][2]);
        out[(n0 + rr)*3 + c] = val * vm[n0 + rr];
    }
}

extern "C" void kernel_launch(void* const* d_in, const int* in_sizes, int n_in,
                              void* d_out, int out_size, void* d_ws, size_t ws_size,
                              hipStream_t stream) {
    const float* x    = (const float*)d_in[0];
    const float* t    = (const float*)d_in[1];
    const float* cell = (const float*)d_in[2];
    const float* x1   = (const float*)d_in[3];
    const float* vm   = (const float*)d_in[4];
    const float* Wsp  = (const float*)d_in[5];
    const float* Wt   = (const float*)d_in[6];
    const float* We   = (const float*)d_in[7];
    const float* Wm   = (const float*)d_in[8];
    const float* Wu   = (const float*)d_in[9];
    const float* wdec = (const float*)d_in[10];
    const int*   ei   = (const int*)d_in[11];
    const int*   tj   = (const int*)d_in[12];
    float* out = (float*)d_out;

    // ws layout (float units):
    float*  ws      = (float*)d_ws;
    uint2*  srec4   = (uint2*)ws;                        // [622592] uint2 = 1245184 f
    float*  pos     = ws + 1245184;                      // [98304]
    unsigned short* rank = (unsigned short*)(pos + 98304);   // [524288] u16 = 262144 f
    int*    rowptr  = (int*)(pos + 98304 + 262144);      // [32772 pad]
    int*    rowptr4 = rowptr + 32772;                    // [8*RP4S = 32800]
    int*    cnt     = rowptr4 + 32800;                   // [32768]
    float*  base_ws = (float*)(cnt + 32768);             // [128]
    unsigned short* wfrag = (unsigned short*)(base_ws + 128);  // [10240]

    hipMemsetAsync(cnt, 0, 32768*sizeof(int), stream);
    k_prep_hist_base<<<2057, 256, 0, stream>>>(x, x1, vm, pos, ei, cnt, rank,
                                               Wsp, Wt, Wm, Wu, We, t, base_ws, wfrag);
    k_scan<<<8, 1024, 0, stream>>>(cnt, rowptr, rowptr4);
    k_sortgeo<<<2176, 256, 0, stream>>>(ei, tj, pos, cell, rowptr, rowptr4, rank, srec4);
    k_edge_all<<<8192, 64, 0, stream>>>(srec4, rowptr, rowptr4, wfrag, base_ws,
                                        Wsp, Wt, wdec, t, vm, out);
}